// Round 4
// baseline (276.119 us; speedup 1.0000x reference)
//
#include <hip/hip_runtime.h>
#include <math.h>

#define INV_SQRT2F 0.7071067811865476f
#define NBLOCKS 512

// Persistent fused kernel with hand-rolled grid barrier (no cooperative API):
//   Phase A: sum(d), sum(d^2)        -> ws[0], ws[1]   (d = |pred-target|)
//   grid barrier (arrival counter cnt[0], all blocks wait)
//   Phase B: sum(erf(d/(var*sqrt2))) -> ws[2]
//   arrival counter cnt[1]; only block 0 waits, finalizes, writes out[0]
//
// Co-residency: __launch_bounds__(256,2) caps VGPR<=256 -> >=2 blocks/CU ->
// all 512 blocks resident on 256 CUs by construction. No deadlock.
// Cross-XCD visibility: device-scope atomicAdd + __threadfence (release) +
// AGENT-scope atomic counter/loads (G16).
__global__ void __launch_bounds__(256, 2)
fused_focal(const float4* __restrict__ pred4, const float4* __restrict__ targ4,
            int n4, int n, float* __restrict__ ws, unsigned int* __restrict__ cnt,
            float* __restrict__ out)
{
    const int stride = gridDim.x * blockDim.x;
    const int tid0   = blockIdx.x * blockDim.x + threadIdx.x;
    const int lane   = threadIdx.x & 63;
    const int wid    = threadIdx.x >> 6;
    __shared__ float ls1[4], ls2[4];

    // ---------------- Phase A: sums ----------------
    float s1 = 0.f, s2 = 0.f;
    int i = tid0;
    for (; i + 7 * stride < n4; i += 8 * stride) {
        float4 p[8], t[8];
#pragma unroll
        for (int u = 0; u < 8; ++u) p[u] = pred4[i + u * stride];
#pragma unroll
        for (int u = 0; u < 8; ++u) t[u] = targ4[i + u * stride];
#pragma unroll
        for (int u = 0; u < 8; ++u) {
            float d0 = fabsf(p[u].x - t[u].x);
            float d1 = fabsf(p[u].y - t[u].y);
            float d2 = fabsf(p[u].z - t[u].z);
            float d3 = fabsf(p[u].w - t[u].w);
            s1 += (d0 + d1) + (d2 + d3);
            s2 += (d0 * d0 + d1 * d1) + (d2 * d2 + d3 * d3);
        }
    }
    for (; i < n4; i += stride) {
        float4 p = pred4[i], t = targ4[i];
        float d0 = fabsf(p.x - t.x), d1 = fabsf(p.y - t.y);
        float d2 = fabsf(p.z - t.z), d3 = fabsf(p.w - t.w);
        s1 += (d0 + d1) + (d2 + d3);
        s2 += (d0 * d0 + d1 * d1) + (d2 * d2 + d3 * d3);
    }
    for (int off = 32; off > 0; off >>= 1) {
        s1 += __shfl_down(s1, off);
        s2 += __shfl_down(s2, off);
    }
    if (lane == 0) { ls1[wid] = s1; ls2[wid] = s2; }
    __syncthreads();
    if (threadIdx.x == 0) {
        atomicAdd(&ws[0], (ls1[0] + ls1[1]) + (ls1[2] + ls1[3]));  // device scope
        atomicAdd(&ws[1], (ls2[0] + ls2[1]) + (ls2[2] + ls2[3]));
        __threadfence();  // release partials before arrival
        __hip_atomic_fetch_add(&cnt[0], 1u, __ATOMIC_ACQ_REL, __HIP_MEMORY_SCOPE_AGENT);
        while (__hip_atomic_load(&cnt[0], __ATOMIC_ACQUIRE, __HIP_MEMORY_SCOPE_AGENT)
               < (unsigned)gridDim.x)
            __builtin_amdgcn_s_sleep(32);
    }
    __syncthreads();   // whole block waits on thread 0's spin

    // ---------------- Phase B: erf sum ----------------
    float sum_d  = __hip_atomic_load(&ws[0], __ATOMIC_RELAXED, __HIP_MEMORY_SCOPE_AGENT);
    float sum_d2 = __hip_atomic_load(&ws[1], __ATOMIC_RELAXED, __HIP_MEMORY_SCOPE_AGENT);
    float nf     = (float)n;
    float mean_d = sum_d / nf;
    float var    = (sum_d2 - sum_d * mean_d) / (nf - 1.0f);
    float k      = INV_SQRT2F / var;

    float s = 0.f;
    i = tid0;
    for (; i + 7 * stride < n4; i += 8 * stride) {
        float4 p[8], t[8];
#pragma unroll
        for (int u = 0; u < 8; ++u) p[u] = pred4[i + u * stride];
#pragma unroll
        for (int u = 0; u < 8; ++u) t[u] = targ4[i + u * stride];
#pragma unroll
        for (int u = 0; u < 8; ++u) {
            s += (erff(fabsf(p[u].x - t[u].x) * k) + erff(fabsf(p[u].y - t[u].y) * k))
               + (erff(fabsf(p[u].z - t[u].z) * k) + erff(fabsf(p[u].w - t[u].w) * k));
        }
    }
    for (; i < n4; i += stride) {
        float4 p = pred4[i], t = targ4[i];
        s += (erff(fabsf(p.x - t.x) * k) + erff(fabsf(p.y - t.y) * k))
           + (erff(fabsf(p.z - t.z) * k) + erff(fabsf(p.w - t.w) * k));
    }
    for (int off = 32; off > 0; off >>= 1)
        s += __shfl_down(s, off);
    __syncthreads();            // ls1 reuse
    if (lane == 0) ls1[wid] = s;
    __syncthreads();
    if (threadIdx.x == 0) {
        atomicAdd(&ws[2], (ls1[0] + ls1[1]) + (ls1[2] + ls1[3]));
        __threadfence();
        __hip_atomic_fetch_add(&cnt[1], 1u, __ATOMIC_ACQ_REL, __HIP_MEMORY_SCOPE_AGENT);
    }

    // ---------------- Finalize: only block 0 waits ----------------
    if (tid0 == 0) {
        while (__hip_atomic_load(&cnt[1], __ATOMIC_ACQUIRE, __HIP_MEMORY_SCOPE_AGENT)
               < (unsigned)gridDim.x)
            __builtin_amdgcn_s_sleep(32);
        float sum_erf = __hip_atomic_load(&ws[2], __ATOMIC_RELAXED, __HIP_MEMORY_SCOPE_AGENT);
        float p       = 1.0f - sum_erf / nf;           // p_correct
        float gamma   = -logf(p);
        float coef    = expf(gamma * logf(1.0f - p));  // (1-p)^gamma
        out[0] = coef * mean_d + logf(var + 1.0f);     // LOSS_WEIGHT = 1
    }
}

extern "C" void kernel_launch(void* const* d_in, const int* in_sizes, int n_in,
                              void* d_out, int out_size, void* d_ws, size_t ws_size,
                              hipStream_t stream) {
    const float4* pred4 = (const float4*)d_in[0];
    const float4* targ4 = (const float4*)d_in[1];
    float* out = (float*)d_out;
    float* ws  = (float*)d_ws;                       // ws[0..2]: float accumulators
    unsigned int* cnt = (unsigned int*)(ws + 4);     // cnt[0..1]: barrier counters
    int n  = in_sizes[0];        // 16777216
    int n4 = n >> 2;

    // ws re-poisoned to 0xAA before every call — zero accumulators + counters
    hipMemsetAsync(d_ws, 0, 8 * sizeof(float), stream);

    fused_focal<<<NBLOCKS, 256, 0, stream>>>(pred4, targ4, n4, n, ws, cnt, out);
}

// Round 5
// 206.165 us; speedup vs baseline: 1.3393x; 1.3393x over previous
//
#include <hip/hip_runtime.h>
#include <math.h>

#define INV_SQRT2F 0.7071067811865476f

// 2048 blocks x 256 threads x 8 float4/thread == n4 exactly: each thread
// issues ONE cluster of 16 independent dwordx4 loads (16 KB/wave in flight),
// sched_barrier(0) pins all 16 loads before any consumption (R4 showed the
// scheduler otherwise interleaves and throttles MLP to ~6 loads).
// launch_bounds(256,4): 128-VGPR budget, >=16 waves/CU.

__global__ void __launch_bounds__(256, 4)
pass_sums(const float4* __restrict__ pred4, const float4* __restrict__ targ4,
          int n4, float* __restrict__ ws) {
    const int stride = gridDim.x * blockDim.x;
    int i = blockIdx.x * blockDim.x + threadIdx.x;
    float s1 = 0.f, s2 = 0.f;

    for (; i + 7 * stride < n4; i += 8 * stride) {
        float4 p[8], t[8];
#pragma unroll
        for (int u = 0; u < 8; ++u) p[u] = pred4[i + u * stride];
#pragma unroll
        for (int u = 0; u < 8; ++u) t[u] = targ4[i + u * stride];
        __builtin_amdgcn_sched_barrier(0);   // all 16 loads issued before any use
#pragma unroll
        for (int u = 0; u < 8; ++u) {
            float d0 = fabsf(p[u].x - t[u].x);
            float d1 = fabsf(p[u].y - t[u].y);
            float d2 = fabsf(p[u].z - t[u].z);
            float d3 = fabsf(p[u].w - t[u].w);
            s1 += (d0 + d1) + (d2 + d3);
            s2 += (d0 * d0 + d1 * d1) + (d2 * d2 + d3 * d3);
        }
    }
    for (; i < n4; i += stride) {            // tail (empty at this problem size)
        float4 p = pred4[i], t = targ4[i];
        float d0 = fabsf(p.x - t.x), d1 = fabsf(p.y - t.y);
        float d2 = fabsf(p.z - t.z), d3 = fabsf(p.w - t.w);
        s1 += (d0 + d1) + (d2 + d3);
        s2 += (d0 * d0 + d1 * d1) + (d2 * d2 + d3 * d3);
    }

    for (int off = 32; off > 0; off >>= 1) {
        s1 += __shfl_down(s1, off);
        s2 += __shfl_down(s2, off);
    }
    __shared__ float ls1[4], ls2[4];
    int lane = threadIdx.x & 63;
    int wid  = threadIdx.x >> 6;
    if (lane == 0) { ls1[wid] = s1; ls2[wid] = s2; }
    __syncthreads();
    if (threadIdx.x == 0) {
        atomicAdd(&ws[0], (ls1[0] + ls1[1]) + (ls1[2] + ls1[3]));
        atomicAdd(&ws[1], (ls2[0] + ls2[1]) + (ls2[2] + ls2[3]));
    }
}

__global__ void __launch_bounds__(256, 4)
pass_erf(const float4* __restrict__ pred4, const float4* __restrict__ targ4,
         int n4, int n, float* __restrict__ ws) {
    float sum_d  = ws[0];
    float sum_d2 = ws[1];
    float nf     = (float)n;
    float mean_d = sum_d / nf;
    float var    = (sum_d2 - sum_d * mean_d) / (nf - 1.0f);
    float k      = INV_SQRT2F / var;

    const int stride = gridDim.x * blockDim.x;
    int i = blockIdx.x * blockDim.x + threadIdx.x;
    float s = 0.f;

    for (; i + 7 * stride < n4; i += 8 * stride) {
        float4 p[8], t[8];
#pragma unroll
        for (int u = 0; u < 8; ++u) p[u] = pred4[i + u * stride];
#pragma unroll
        for (int u = 0; u < 8; ++u) t[u] = targ4[i + u * stride];
        __builtin_amdgcn_sched_barrier(0);
#pragma unroll
        for (int u = 0; u < 8; ++u) {
            s += (erff(fabsf(p[u].x - t[u].x) * k) + erff(fabsf(p[u].y - t[u].y) * k))
               + (erff(fabsf(p[u].z - t[u].z) * k) + erff(fabsf(p[u].w - t[u].w) * k));
        }
    }
    for (; i < n4; i += stride) {
        float4 p = pred4[i], t = targ4[i];
        s += (erff(fabsf(p.x - t.x) * k) + erff(fabsf(p.y - t.y) * k))
           + (erff(fabsf(p.z - t.z) * k) + erff(fabsf(p.w - t.w) * k));
    }

    for (int off = 32; off > 0; off >>= 1)
        s += __shfl_down(s, off);
    __shared__ float ls[4];
    int lane = threadIdx.x & 63;
    int wid  = threadIdx.x >> 6;
    if (lane == 0) ls[wid] = s;
    __syncthreads();
    if (threadIdx.x == 0)
        atomicAdd(&ws[2], (ls[0] + ls[1]) + (ls[2] + ls[3]));
}

__global__ void finalize(const float* __restrict__ ws, float* __restrict__ out, int n) {
    float sum_d   = ws[0];
    float sum_d2  = ws[1];
    float sum_erf = ws[2];
    float nf      = (float)n;
    float mean_d  = sum_d / nf;
    float var     = (sum_d2 - sum_d * mean_d) / (nf - 1.0f);
    float p       = 1.0f - sum_erf / nf;          // p_correct
    float gamma   = -logf(p);
    float coef    = expf(gamma * logf(1.0f - p)); // (1-p)^gamma
    out[0] = coef * mean_d + logf(var + 1.0f);    // LOSS_WEIGHT = 1
}

extern "C" void kernel_launch(void* const* d_in, const int* in_sizes, int n_in,
                              void* d_out, int out_size, void* d_ws, size_t ws_size,
                              hipStream_t stream) {
    const float4* pred4 = (const float4*)d_in[0];
    const float4* targ4 = (const float4*)d_in[1];
    float* out = (float*)d_out;
    float* ws  = (float*)d_ws;
    int n  = in_sizes[0];        // 16777216
    int n4 = n >> 2;

    // ws re-poisoned to 0xAA before every call — zero the 3 accumulators
    hipMemsetAsync(d_ws, 0, 3 * sizeof(float), stream);

    const int block = 256;
    const int grid  = 2048;      // 2048*256*8 float4 == n4 exactly: one-shot clusters

    pass_sums<<<grid, block, 0, stream>>>(pred4, targ4, n4, ws);
    pass_erf<<<grid, block, 0, stream>>>(pred4, targ4, n4, n, ws);
    finalize<<<1, 1, 0, stream>>>(ws, out, n);
}